// Round 9
// baseline (372.389 us; speedup 1.0000x reference)
//
#include <hip/hip_runtime.h>
#include <stdint.h>
#include <stddef.h>

typedef int v4i  __attribute__((ext_vector_type(4)));
typedef int v16i __attribute__((ext_vector_type(16)));

#define KCH  256                 // K-chunk per LDS buffer (16 granules of 16 B)
#define BUFB (128 * 256)         // 32 KB per buffer: [row][slot] 16B units
#define LDSB (2 * BUFB)          // 64 KB -> 2 blocks/CU, 16 waves/CU

// async global->LDS, 16B per lane. Global addr per-lane; LDS dest wave-uniform
// base + lane*16.
__device__ __forceinline__ void gl_lds16(const uint8_t* g, uint8_t* l) {
    __builtin_amdgcn_global_load_lds(
        (const __attribute__((address_space(1))) uint32_t*)g,
        (__attribute__((address_space(3))) uint32_t*)l,
        16, 0, 0);
}

// Software q8 (float path, quant kernel only): EXACT reference semantics.
__device__ __forceinline__ float q8f(float v) {
    float a = fabsf(v);
    int e = (int)(__float_as_uint(a) >> 23) - 127;
    e = e < -6 ? -6 : (e > 8 ? 8 : e);
    float step  = __uint_as_float((uint32_t)(e - 3 + 127) << 23);  // 2^(e-3)
    float rstep = __uint_as_float((uint32_t)(3 - e + 127) << 23);  // 2^(3-e)
    float q = fminf(rintf(a * rstep) * step, 448.0f);
    return v < 0.0f ? -q : q;
}
__device__ __forceinline__ int qm(float v) {  // q8 value * 512 (exact int)
    return (int)rintf(q8f(v) * 512.0f);
}

// integer round-half-even shift: RNE(a / 2^s), a >= 0, s >= 1
__device__ __forceinline__ uint32_t rne_sh(uint32_t a, int s) {
    uint32_t t = a >> s;
    uint32_t rem = a & ((1u << s) - 1u);
    uint32_t half = 1u << (s - 1);
    t += (rem > half) || (rem == half && (t & 1u));
    return t;
}

// One fused quant launch: region 0 -> x (hi/lo planes), 1 -> w1, 2 -> w2.
__global__ __launch_bounds__(256) void quant_all_kernel(
    const float* __restrict__ x,  uint32_t* __restrict__ xh, uint32_t* __restrict__ xl,
    const float* __restrict__ w1, uint32_t* __restrict__ w1m,
    const float* __restrict__ w2, uint32_t* __restrict__ w2m,
    int n4x, int n4w1, int n4w2) {
    int i = blockIdx.x * 256 + threadIdx.x;
    if (i < n4x) {
        float4 v = ((const float4*)x)[i];
        int m0 = qm(v.x), m1 = qm(v.y), m2 = qm(v.z), m3 = qm(v.w);
        xh[i] = ((uint32_t)((m0 >> 5) & 0xff)) | ((uint32_t)((m1 >> 5) & 0xff) << 8) |
                ((uint32_t)((m2 >> 5) & 0xff) << 16) | ((uint32_t)((m3 >> 5) & 0xff) << 24);
        xl[i] = ((uint32_t)(m0 & 31)) | ((uint32_t)(m1 & 31) << 8) |
                ((uint32_t)(m2 & 31) << 16) | ((uint32_t)(m3 & 31) << 24);
    } else if (i < n4x + n4w1) {
        int j = i - n4x;
        float4 v = ((const float4*)w1)[j];
        w1m[j] = ((uint32_t)(qm(v.x) & 0xff)) | ((uint32_t)(qm(v.y) & 0xff) << 8) |
                 ((uint32_t)(qm(v.z) & 0xff) << 16) | ((uint32_t)(qm(v.w) & 0xff) << 24);
    } else if (i < n4x + n4w1 + n4w2) {
        int j = i - n4x - n4w1;
        float4 v = ((const float4*)w2)[j];
        w2m[j] = ((uint32_t)(qm(v.x) & 0xff)) | ((uint32_t)(qm(v.y) & 0xff) << 8) |
                 ((uint32_t)(qm(v.z) & 0xff) << 16) | ((uint32_t)(qm(v.w) & 0xff) << 24);
    }
}

// Stage one K-chunk of B into LDS buffer dst (8 waves, 4 transfers each).
// Layout: [row][slot], slot = granule ^ (row & 15); 256 B per row.
// Each call: 4 consecutive rows, lanes permuted within rows -> fully
// line-coalesced global reads; fragment reads are 2-way (free).
__device__ __forceinline__ void stage_chunk(
    const uint8_t* __restrict__ Bm, uint8_t* dst,
    int bn, int K, int kc, int wave, int lane) {
    const int r0 = lane >> 4;   // row within quad
    const int sl = lane & 15;   // LDS slot
#pragma unroll
    for (int s = 0; s < 4; ++s) {
        const int qd  = wave * 4 + s;        // quad 0..31
        const int row = qd * 4 + r0;         // 0..127
        const int g   = sl ^ (row & 15);     // global granule for this slot
        gl_lds16(Bm + (size_t)(bn * 128 + row) * K + kc + g * 16,
                 dst + qd * 1024 + lane * 16);
    }
}

// C[M,N] = (32*Ah + Al)[M,K] * Bm[N,K]^T * 2^-18, exact i32 accumulation via
// mfma_i32_32x32x32_i8. 512 threads = 8 waves; block tile 128x128; wave tile
// 32x64 (row strip wave>>1, col half wave&1). acc = 64 AGPRs -> 4 waves/SIMD
// (16 waves/CU with 2 blocks) for TLP latency hiding. B double-buffered in
// LDS (XOR-swizzled). A streamed global->VGPR per k0.
// EPI=0: q8+ReLU -> hi/lo i8 planes. EPI=1: q8 fp32.
template <int EPI>
__global__ __launch_bounds__(512, 4) void gemm_i8_big(
    const uint8_t* __restrict__ Ah, const uint8_t* __restrict__ Al,
    const uint8_t* __restrict__ Bm,
    void* __restrict__ Ch, void* __restrict__ Cl,
    int M, int N, int K) {
    extern __shared__ uint8_t sB[];  // 2 x BUFB

    const int tid  = threadIdx.x;
    const int lane = tid & 63;
    const int wave = tid >> 6;     // 8 waves
    const int ws   = wave >> 1;    // row strip 0..3
    const int ch   = wave & 1;     // col half 0..1
    const int col  = lane & 31;    // col within 32-tile / A row within 32
    const int kh   = lane >> 5;    // 16B k-granule within each 32-k window
    const int xm   = col & 15;     // slot XOR key
    const int bm = blockIdx.x, bn = blockIdx.y;

    v16i acc[2][2];
#pragma unroll
    for (int p = 0; p < 2; ++p)
#pragma unroll
        for (int j = 0; j < 2; ++j) acc[p][j] = (v16i)0;

    // A pointers: lane covers row=col of the strip, granule kh
    const size_t arow = (size_t)(bm * 128 + ws * 32 + col);
    const uint8_t* pAh = Ah + arow * K + kh * 16;
    const uint8_t* pAl = Al + arow * K + kh * 16;

    int rowoff[2];
#pragma unroll
    for (int j = 0; j < 2; ++j) rowoff[j] = (ch * 64 + j * 32 + col) * 256;

    const int NC = K / KCH;
    stage_chunk(Bm, sB, bn, K, 0, wave, lane);

    for (int c = 0; c < NC; ++c) {
        __syncthreads();  // per-wave vmcnt(0) drain -> stage(c) complete
        const int kc = c * KCH;
        if (c + 1 < NC)  // stage next chunk, overlaps this chunk's compute
            stage_chunk(Bm, sB + ((c + 1) & 1) * BUFB, bn, K, kc + KCH, wave, lane);

        const uint8_t* buf = sB + (c & 1) * BUFB;
#pragma unroll
        for (int t = 0; t < 8; ++t) {
            v4i a0 = *(const v4i*)(pAh + kc + t * 32);
            v4i a1 = *(const v4i*)(pAl + kc + t * 32);
            const int slot = ((2 * t + kh) & 15) ^ xm;
            v4i b0 = *(const v4i*)(buf + rowoff[0] + slot * 16);
            v4i b1 = *(const v4i*)(buf + rowoff[1] + slot * 16);
            acc[0][0] = __builtin_amdgcn_mfma_i32_32x32x32_i8(a0, b0, acc[0][0], 0, 0, 0);
            acc[1][0] = __builtin_amdgcn_mfma_i32_32x32x32_i8(a1, b0, acc[1][0], 0, 0, 0);
            acc[0][1] = __builtin_amdgcn_mfma_i32_32x32x32_i8(a0, b1, acc[0][1], 0, 0, 0);
            acc[1][1] = __builtin_amdgcn_mfma_i32_32x32x32_i8(a1, b1, acc[1][1], 0, 0, 0);
        }
    }

    // C/D layout (32x32): col = lane&31, row = (reg&3) + 8*(reg>>2) + 4*(lane>>5)
    const int cg0 = bn * 128 + ch * 64 + col;
    const int rg0 = bm * 128 + ws * 32 + 4 * kh;
#pragma unroll
    for (int j = 0; j < 2; ++j) {
#pragma unroll
        for (int reg = 0; reg < 16; ++reg) {
            int mt = acc[0][j][reg] * 32 + acc[1][j][reg];  // exact, |mt| < 2^24
            size_t idx = (size_t)(rg0 + (reg & 3) + 8 * (reg >> 2)) * N
                       + (size_t)(cg0 + j * 32);
            if (EPI == 0) {
                // q8 (int RNE on 2^-18 grid) + ReLU -> h in 2^-9 units -> hi/lo
                uint8_t hb = 0, lb = 0;
                if (mt > 0) {
                    int s = 28 - __builtin_clz((uint32_t)mt);
                    if (s < 9) s = 9;
                    int mh = (int)(rne_sh((uint32_t)mt, s) << (s - 9));
                    hb = (uint8_t)(mh >> 5);
                    lb = (uint8_t)(mh & 31);
                }
                ((uint8_t*)Ch)[idx] = hb;
                ((uint8_t*)Cl)[idx] = lb;
            } else {
                uint32_t a = mt < 0 ? (uint32_t)(-mt) : (uint32_t)mt;
                float v = 0.0f;
                if (a) {
                    int s = 28 - __builtin_clz(a);
                    if (s < 9) s = 9;
                    v = (float)(rne_sh(a, s) << s) * 0x1p-18f;  // exact
                    if (mt < 0) v = -v;
                }
                ((float*)Ch)[idx] = v;
            }
        }
    }
}

extern "C" void kernel_launch(void* const* d_in, const int* in_sizes, int n_in,
                              void* d_out, int out_size, void* d_ws, size_t ws_size,
                              hipStream_t stream) {
    const int Bsz = 8192, DIN = 1024, DH = 4096, DOUT = 1024;
    const float* x  = (const float*)d_in[0];
    const float* w1 = (const float*)d_in[1];
    const float* w2 = (const float*)d_in[2];
    float* out = (float*)d_out;

    uint8_t* ws  = (uint8_t*)d_ws;
    uint8_t* xh  = ws;                            //  8 MB
    uint8_t* xl  = xh  + (size_t)Bsz * DIN;       //  8 MB
    uint8_t* w1m = xl  + (size_t)Bsz * DIN;       //  4 MB
    uint8_t* w2m = w1m + (size_t)DH  * DIN;       //  4 MB
    uint8_t* hh  = w2m + (size_t)DOUT * DH;       // 32 MB
    uint8_t* hl  = hh  + (size_t)Bsz * DH;        // 32 MB

    static bool attr_done = false;
    if (!attr_done) {
        hipFuncSetAttribute((const void*)gemm_i8_big<0>,
                            hipFuncAttributeMaxDynamicSharedMemorySize, LDSB);
        hipFuncSetAttribute((const void*)gemm_i8_big<1>,
                            hipFuncAttributeMaxDynamicSharedMemorySize, LDSB);
        attr_done = true;
    }

    const int n4x = Bsz * DIN / 4, n4w1 = DH * DIN / 4, n4w2 = DOUT * DH / 4;
    quant_all_kernel<<<(n4x + n4w1 + n4w2) / 256, 256, 0, stream>>>(
        x, (uint32_t*)xh, (uint32_t*)xl, w1, (uint32_t*)w1m, w2, (uint32_t*)w2m,
        n4x, n4w1, n4w2);

    // fc1: h = relu(q8(x8 @ w1q^T)) -> hi/lo  [8192,4096]
    dim3 g1(Bsz / 128, DH / 128);   // 64 x 32 = 2048 blocks
    gemm_i8_big<0><<<g1, 512, LDSB, stream>>>(xh, xl, w1m, (void*)hh, (void*)hl, Bsz, DH, DIN);

    // fc2: out = q8(h @ w2q^T)  [8192,1024] fp32
    dim3 g2(Bsz / 128, DOUT / 128); // 64 x 8 = 512 blocks
    gemm_i8_big<1><<<g2, 512, LDSB, stream>>>(hh, hl, w2m, (void*)out, nullptr, Bsz, DOUT, DH);
}

// Round 10
// 255.473 us; speedup vs baseline: 1.4576x; 1.4576x over previous
//
#include <hip/hip_runtime.h>
#include <stdint.h>
#include <stddef.h>

typedef int v4i  __attribute__((ext_vector_type(4)));
typedef int v16i __attribute__((ext_vector_type(16)));

#define KCH  256                 // K-chunk per LDS buffer (16 granules of 16 B)
#define BUFB (128 * 256)         // 32 KB per buffer: [row][slot] 16B units
#define LDSB (2 * BUFB)          // 64 KB -> 2 blocks/CU

// async global->LDS, 16B per lane.
__device__ __forceinline__ void gl_lds16(const uint8_t* g, uint8_t* l) {
    __builtin_amdgcn_global_load_lds(
        (const __attribute__((address_space(1))) uint32_t*)g,
        (__attribute__((address_space(3))) uint32_t*)l,
        16, 0, 0);
}

// Software q8: EXACT reference semantics (floor(log2), clamp[-6,8], half-even, sat 448).
__device__ __forceinline__ float q8f(float v) {
    float a = fabsf(v);
    int e = (int)(__float_as_uint(a) >> 23) - 127;
    e = e < -6 ? -6 : (e > 8 ? 8 : e);
    float step  = __uint_as_float((uint32_t)(e - 3 + 127) << 23);  // 2^(e-3)
    float rstep = __uint_as_float((uint32_t)(3 - e + 127) << 23);  // 2^(3-e)
    float q = fminf(rintf(a * rstep) * step, 448.0f);
    return v < 0.0f ? -q : q;
}
__device__ __forceinline__ int qm(float v) {  // q8 value * 512 (exact int)
    return (int)rintf(q8f(v) * 512.0f);
}

// integer round-half-even shift: RNE(a / 2^s), a >= 0, s >= 1
__device__ __forceinline__ uint32_t rne_sh(uint32_t a, int s) {
    uint32_t t = a >> s;
    uint32_t rem = a & ((1u << s) - 1u);
    uint32_t half = 1u << (s - 1);
    t += (rem > half) || (rem == half && (t & 1u));
    return t;
}

// Fused quant. x is written in PACKED fragment order:
//   addr(r,g,b) = ((r>>5)*(K/16) + g)*512 + (r&31)*16 + b   (K=1024, 64 granules)
// so the GEMM's A-loads are lane-linear 1KB bursts. w1/w2 stay row-major.
__global__ __launch_bounds__(256) void quant_all_kernel(
    const float* __restrict__ x,  uint32_t* __restrict__ xh, uint32_t* __restrict__ xl,
    const float* __restrict__ w1, uint32_t* __restrict__ w1m,
    const float* __restrict__ w2, uint32_t* __restrict__ w2m,
    int n4x, int n4w1, int n4w2) {
    int i = blockIdx.x * 256 + threadIdx.x;
    if (i < n4x) {
        float4 v = ((const float4*)x)[i];
        int m0 = qm(v.x), m1 = qm(v.y), m2 = qm(v.z), m3 = qm(v.w);
        uint32_t h = ((uint32_t)((m0 >> 5) & 0xff)) | ((uint32_t)((m1 >> 5) & 0xff) << 8) |
                     ((uint32_t)((m2 >> 5) & 0xff) << 16) | ((uint32_t)((m3 >> 5) & 0xff) << 24);
        uint32_t l = ((uint32_t)(m0 & 31)) | ((uint32_t)(m1 & 31) << 8) |
                     ((uint32_t)(m2 & 31) << 16) | ((uint32_t)(m3 & 31) << 24);
        int r = i >> 8, c4 = i & 255;                     // K/4 = 256 float4 per row
        int pi = ((r >> 5) * 64 + (c4 >> 2)) * 128 + (r & 31) * 4 + (c4 & 3);
        xh[pi] = h;
        xl[pi] = l;
    } else if (i < n4x + n4w1) {
        int j = i - n4x;
        float4 v = ((const float4*)w1)[j];
        w1m[j] = ((uint32_t)(qm(v.x) & 0xff)) | ((uint32_t)(qm(v.y) & 0xff) << 8) |
                 ((uint32_t)(qm(v.z) & 0xff) << 16) | ((uint32_t)(qm(v.w) & 0xff) << 24);
    } else if (i < n4x + n4w1 + n4w2) {
        int j = i - n4x - n4w1;
        float4 v = ((const float4*)w2)[j];
        w2m[j] = ((uint32_t)(qm(v.x) & 0xff)) | ((uint32_t)(qm(v.y) & 0xff) << 8) |
                 ((uint32_t)(qm(v.z) & 0xff) << 16) | ((uint32_t)(qm(v.w) & 0xff) << 24);
    }
}

// Stage one K-chunk of B (row-major) into LDS [row][slot], slot = g ^ (row&15).
// Per inst: 4 consecutive rows, 16 fully-used lines. 4 waves, 8 insts each.
__device__ __forceinline__ void stage_chunk(
    const uint8_t* __restrict__ Bm, uint8_t* dst,
    int bn, int K, int kc, int wave, int lane) {
    const int r0 = lane >> 4;
    const int sl = lane & 15;
#pragma unroll
    for (int s = 0; s < 8; ++s) {
        const int qd  = wave * 8 + s;
        const int row = qd * 4 + r0;
        const int g   = sl ^ (row & 15);
        gl_lds16(Bm + (size_t)(bn * 128 + row) * K + kc + g * 16,
                 dst + qd * 1024 + lane * 16);
    }
}

// C = (32*Ah + Al) * Bm^T * 2^-18, exact i32 via mfma_i32_32x32x32_i8.
// A is PACKED (fragment-order): per-t load = base + t*1024 + lane*16 (lane-linear).
// 256 thr = 4 waves, block tile 128x128, wave tile 32x128, 2 blocks/CU.
// EPI=0: q8+ReLU -> hi/lo planes written PACKED (K=N for next layer). EPI=1: fp32 row-major.
template <int EPI>
__global__ __launch_bounds__(256, 2) void gemm_i8_big(
    const uint8_t* __restrict__ Ah, const uint8_t* __restrict__ Al,
    const uint8_t* __restrict__ Bm,
    void* __restrict__ Ch, void* __restrict__ Cl,
    int M, int N, int K) {
    extern __shared__ uint8_t sB[];  // 2 x BUFB

    const int tid  = threadIdx.x;
    const int lane = tid & 63;
    const int wave = tid >> 6;     // 4 waves = 4 row strips
    const int col  = lane & 31;
    const int kh   = lane >> 5;
    const int xm   = col & 15;
    const int bm = blockIdx.x, bn = blockIdx.y;

    v16i acc[2][4];
#pragma unroll
    for (int p = 0; p < 2; ++p)
#pragma unroll
        for (int j = 0; j < 4; ++j) acc[p][j] = (v16i)0;

    // packed A: row-block (bm*4 + wave), sequential 1KB per t-step across all K
    const size_t abase = (size_t)(bm * 4 + wave) * (K >> 4) * 512 + lane * 16;
    const uint8_t* pAh = Ah + abase;
    const uint8_t* pAl = Al + abase;
    const int NT = K >> 5;         // total t-steps (1KB each)

    int rowoff[4];
#pragma unroll
    for (int j = 0; j < 4; ++j) rowoff[j] = (j * 32 + col) * 256;

    const int NC = K / KCH;
    stage_chunk(Bm, sB, bn, K, 0, wave, lane);

    // preload first A step
    v4i a0 = *(const v4i*)(pAh);
    v4i a1 = *(const v4i*)(pAl);

    for (int c = 0; c < NC; ++c) {
        __syncthreads();  // stage(c) complete
        if (c + 1 < NC)
            stage_chunk(Bm, sB + ((c + 1) & 1) * BUFB, bn, K, (c + 1) * KCH, wave, lane);

        const uint8_t* buf = sB + (c & 1) * BUFB;
#pragma unroll
        for (int t = 0; t < 8; ++t) {
            const int gt = c * 8 + t;
            v4i na0 = a0, na1 = a1;
            if (gt + 1 < NT) {  // wave-uniform; sequential 1KB prefetch
                na0 = *(const v4i*)(pAh + (size_t)(gt + 1) * 1024);
                na1 = *(const v4i*)(pAl + (size_t)(gt + 1) * 1024);
            }
            const int slot = ((2 * t + kh) & 15) ^ xm;
            v4i b[4];
#pragma unroll
            for (int j = 0; j < 4; ++j)
                b[j] = *(const v4i*)(buf + rowoff[j] + slot * 16);
#pragma unroll
            for (int j = 0; j < 4; ++j) {
                acc[0][j] = __builtin_amdgcn_mfma_i32_32x32x32_i8(a0, b[j], acc[0][j], 0, 0, 0);
                acc[1][j] = __builtin_amdgcn_mfma_i32_32x32x32_i8(a1, b[j], acc[1][j], 0, 0, 0);
            }
            a0 = na0; a1 = na1;
        }
    }

    // C/D layout (32x32): col = lane&31, row = (reg&3) + 8*(reg>>2) + 4*(lane>>5)
    const int Gn = N >> 4;  // granules per output row (packed dest, EPI=0)
    const int rb = bm * 4 + wave;
#pragma unroll
    for (int j = 0; j < 4; ++j) {
        const int colk = bn * 128 + j * 32 + col;
#pragma unroll
        for (int reg = 0; reg < 16; ++reg) {
            int mt = acc[0][j][reg] * 32 + acc[1][j][reg];  // exact, |mt| < 2^24
            const int rw = 4 * kh + (reg & 3) + 8 * (reg >> 2);  // row within 32
            if (EPI == 0) {
                uint8_t hb = 0, lb = 0;
                if (mt > 0) {
                    int s = 28 - __builtin_clz((uint32_t)mt);
                    if (s < 9) s = 9;
                    int mh = (int)(rne_sh((uint32_t)mt, s) << (s - 9));
                    hb = (uint8_t)(mh >> 5);
                    lb = (uint8_t)(mh & 31);
                }
                size_t pa = ((size_t)rb * Gn + (colk >> 4)) * 512 + rw * 16 + (colk & 15);
                ((uint8_t*)Ch)[pa] = hb;
                ((uint8_t*)Cl)[pa] = lb;
            } else {
                uint32_t a = mt < 0 ? (uint32_t)(-mt) : (uint32_t)mt;
                float v = 0.0f;
                if (a) {
                    int s = 28 - __builtin_clz(a);
                    if (s < 9) s = 9;
                    v = (float)(rne_sh(a, s) << s) * 0x1p-18f;  // exact
                    if (mt < 0) v = -v;
                }
                ((float*)Ch)[(size_t)(rb * 32 + rw) * N + colk] = v;
            }
        }
    }
}

extern "C" void kernel_launch(void* const* d_in, const int* in_sizes, int n_in,
                              void* d_out, int out_size, void* d_ws, size_t ws_size,
                              hipStream_t stream) {
    const int Bsz = 8192, DIN = 1024, DH = 4096, DOUT = 1024;
    const float* x  = (const float*)d_in[0];
    const float* w1 = (const float*)d_in[1];
    const float* w2 = (const float*)d_in[2];
    float* out = (float*)d_out;

    uint8_t* ws  = (uint8_t*)d_ws;
    uint8_t* xh  = ws;                            //  8 MB (packed)
    uint8_t* xl  = xh  + (size_t)Bsz * DIN;       //  8 MB (packed)
    uint8_t* w1m = xl  + (size_t)Bsz * DIN;       //  4 MB
    uint8_t* w2m = w1m + (size_t)DH  * DIN;       //  4 MB
    uint8_t* hh  = w2m + (size_t)DOUT * DH;       // 32 MB (packed)
    uint8_t* hl  = hh  + (size_t)Bsz * DH;        // 32 MB (packed)

    static bool attr_done = false;
    if (!attr_done) {
        hipFuncSetAttribute((const void*)gemm_i8_big<0>,
                            hipFuncAttributeMaxDynamicSharedMemorySize, LDSB);
        hipFuncSetAttribute((const void*)gemm_i8_big<1>,
                            hipFuncAttributeMaxDynamicSharedMemorySize, LDSB);
        attr_done = true;
    }

    const int n4x = Bsz * DIN / 4, n4w1 = DH * DIN / 4, n4w2 = DOUT * DH / 4;
    quant_all_kernel<<<(n4x + n4w1 + n4w2) / 256, 256, 0, stream>>>(
        x, (uint32_t*)xh, (uint32_t*)xl, w1, (uint32_t*)w1m, w2, (uint32_t*)w2m,
        n4x, n4w1, n4w2);

    // fc1: h = relu(q8(x8 @ w1q^T)) -> packed hi/lo  [8192,4096]
    dim3 g1(Bsz / 128, DH / 128);   // 64 x 32 = 2048 blocks
    gemm_i8_big<0><<<g1, 256, LDSB, stream>>>(xh, xl, w1m, (void*)hh, (void*)hl, Bsz, DH, DIN);

    // fc2: out = q8(h @ w2q^T)  [8192,1024] fp32
    dim3 g2(Bsz / 128, DOUT / 128); // 64 x 8 = 512 blocks
    gemm_i8_big<1><<<g2, 256, LDSB, stream>>>(hh, hl, w2m, (void*)out, nullptr, Bsz, DOUT, DH);
}